// Round 1
// baseline (1256.894 us; speedup 1.0000x reference)
//
#include <hip/hip_runtime.h>
#include <stdint.h>

#define N_NODES 50000
#define N_EDGES 200000
#define N_GROUPS (N_EDGES / 16)   // 12500 groups of 16 edges
#define SQ3 0.5773502691896258f
#define ALPHAC 0.17677669529663687f
#define EPSC 1e-5f

typedef __attribute__((ext_vector_type(8))) __bf16 bf16x8;
typedef __attribute__((ext_vector_type(8))) unsigned short u16x8;
typedef __attribute__((ext_vector_type(4))) float f32x4;
typedef __attribute__((ext_vector_type(4))) unsigned int u32x4;

static __device__ __forceinline__ unsigned short bf16_rne(float f) {
  union { float f; unsigned int u; } v; v.f = f;
  return (unsigned short)((v.u + 0x7fffu + ((v.u >> 16) & 1u)) >> 16);
}

// ---------------------------------------------------------------------------
// K0: transpose+convert weights to bf16.  w1T[c*64+j] = w1[j,c]; w2T[c*64+j] = w2[j,c]
// ---------------------------------------------------------------------------
__global__ void k_convert(const float* __restrict__ w1, const float* __restrict__ w2,
                          unsigned short* __restrict__ w1T, unsigned short* __restrict__ w2T) {
  int idx = blockIdx.x * 256 + threadIdx.x;   // grid covers 65536
  if (idx < 64 * 64) {
    int c = idx >> 6, j = idx & 63;
    w1T[idx] = bf16_rne(w1[j * 64 + c]);
  }
  if (idx < 1024 * 64) {
    int c = idx >> 6, j = idx & 63;
    w2T[idx] = bf16_rne(w2[j * 1024 + c]);
  }
}

// ---------------------------------------------------------------------------
// K1: H = relu(edge_attr @ w1 + b1)  -> bf16 Hbf[E][64]
// Transposed MFMA: D[row=c, col=e] so each lane stores 4 consecutive c for one e.
// A = w1^T (rows=c, k=j), B = edge_attr row (k=j, col=e).
// ---------------------------------------------------------------------------
__global__ __launch_bounds__(256) void k_gemm1(
    const float* __restrict__ ea, const unsigned short* __restrict__ w1T,
    const float* __restrict__ b1, unsigned short* __restrict__ hbf) {
  const int tid = threadIdx.x;
  const int lane = tid & 63;
  const int wid = tid >> 6;
  const int l15 = lane & 15, rg = lane >> 4;

  // Preload all A-fragments (w1T) + b1 initializers into registers (shared weights)
  bf16x8 afr[4][2];
  f32x4 binit[4];
#pragma unroll
  for (int cf = 0; cf < 4; cf++) {
#pragma unroll
    for (int ks = 0; ks < 2; ks++)
      afr[cf][ks] = *(const bf16x8*)(w1T + (cf * 16 + l15) * 64 + ks * 32 + rg * 8);
    binit[cf] = *(const f32x4*)(b1 + cf * 16 + rg * 4);
  }

  const int g0 = blockIdx.x * 32 + wid * 8;
#pragma unroll 1
  for (int gi = 0; gi < 8; gi++) {
    int g = g0 + gi;
    if (g >= N_GROUPS) break;
    const long e = (long)g * 16 + l15;
    const float* row = ea + e * 64;
    bf16x8 bfr[2];
#pragma unroll
    for (int ks = 0; ks < 2; ks++) {
      f32x4 lo = *(const f32x4*)(row + ks * 32 + rg * 8);
      f32x4 hi = *(const f32x4*)(row + ks * 32 + rg * 8 + 4);
      u16x8 u;
      u[0] = bf16_rne(lo[0]); u[1] = bf16_rne(lo[1]); u[2] = bf16_rne(lo[2]); u[3] = bf16_rne(lo[3]);
      u[4] = bf16_rne(hi[0]); u[5] = bf16_rne(hi[1]); u[6] = bf16_rne(hi[2]); u[7] = bf16_rne(hi[3]);
      bfr[ks] = __builtin_bit_cast(bf16x8, u);
    }
#pragma unroll
    for (int cf = 0; cf < 4; cf++) {
      f32x4 d = binit[cf];
      d = __builtin_amdgcn_mfma_f32_16x16x32_bf16(afr[cf][0], bfr[0], d, 0, 0, 0);
      d = __builtin_amdgcn_mfma_f32_16x16x32_bf16(afr[cf][1], bfr[1], d, 0, 0, 0);
      unsigned int p0 = (unsigned)bf16_rne(fmaxf(d[0], 0.f)) | ((unsigned)bf16_rne(fmaxf(d[1], 0.f)) << 16);
      unsigned int p1 = (unsigned)bf16_rne(fmaxf(d[2], 0.f)) | ((unsigned)bf16_rne(fmaxf(d[3], 0.f)) << 16);
      unsigned int* dstp = (unsigned int*)(hbf + e * 64 + cf * 16 + rg * 4);
      dstp[0] = p0; dstp[1] = p1;
    }
  }
}

// ---------------------------------------------------------------------------
// K2: fused  w = h@w2 + b2  ->  tensor product  ->  atomic scatter into agg.
// Per wave: 64 edges (4 groups of 16). Per t-chunk (256 w2 cols) staged in LDS
// (XOR-swizzled), compute W^T fragments D[row=k, col=edge] and contract with
// lane-resident a-values immediately. Never writes W to memory.
// ---------------------------------------------------------------------------
__global__ __launch_bounds__(256, 2) void k_fused(
    const unsigned short* __restrict__ hbf, const unsigned short* __restrict__ w2T,
    const float* __restrict__ b2, const float* __restrict__ na,
    const float* __restrict__ sh, const int* __restrict__ ei,
    float* __restrict__ agg, float* __restrict__ cnt) {
  __shared__ unsigned short w2ld[256 * 64];  // 32KB, swizzled: slot ^= (row&7)
  const int tid = threadIdx.x;
  const int lane = tid & 63;
  const int wid = tid >> 6;
  const int l15 = lane & 15, rg = lane >> 4;

  const long eb_wave = (long)blockIdx.x * 256 + wid * 64;

  int srcn[4], dstn[4], vld[4];
  float ss[4], sv[4][3];
  bf16x8 bfr[4][2];
#pragma unroll
  for (int eg = 0; eg < 4; eg++) {
    long ebase = eb_wave + eg * 16;
    vld[eg] = (ebase < N_EDGES);
    long e = vld[eg] ? (ebase + l15) : (long)l15;
    srcn[eg] = ei[e];
    dstn[eg] = ei[N_EDGES + e];
    f32x4 s4 = *(const f32x4*)(sh + e * 4);
    ss[eg] = s4[0]; sv[eg][0] = s4[1]; sv[eg][1] = s4[2]; sv[eg][2] = s4[3];
#pragma unroll
    for (int ks = 0; ks < 2; ks++)
      bfr[eg][ks] = *(const bf16x8*)(hbf + e * 64 + ks * 32 + rg * 8);
  }

  float outs[4][4];        // out_s accum [eg][reg], k = rg*4+reg
  float outv[4][4][3];     // out_v accum [eg][reg][m]
#pragma unroll
  for (int eg = 0; eg < 4; eg++)
#pragma unroll
    for (int r = 0; r < 4; r++) {
      outs[eg][r] = 0.f;
      outv[eg][r][0] = 0.f; outv[eg][r][1] = 0.f; outv[eg][r][2] = 0.f;
    }

#pragma unroll 1
  for (int t = 0; t < 4; t++) {
    __syncthreads();
    // stage w2T chunk t into LDS with XOR swizzle (write side)
#pragma unroll
    for (int it = 0; it < 8; it++) {
      int idx16 = it * 256 + tid;
      int rc = idx16 >> 3;
      int sl = idx16 & 7;
      u32x4 v = *(const u32x4*)(w2T + ((t * 256 + rc) * 64 + sl * 8));
      *(u32x4*)((char*)w2ld + rc * 128 + ((sl ^ (rc & 7)) << 4)) = v;
    }
    __syncthreads();

    float tsv[4][4];
    if (t == 2) {
#pragma unroll
      for (int eg = 0; eg < 4; eg++)
#pragma unroll
        for (int r = 0; r < 4; r++) tsv[eg][r] = 0.f;
    }

#pragma unroll 1
    for (int ic = 0; ic < 4; ic++) {
      float ax[4][4];     // xs chunk (t=0,2)
      float axv[4][12];   // xv chunk (t=1,3)
      if (t == 0 || t == 2) {
#pragma unroll
        for (int eg = 0; eg < 4; eg++) {
          f32x4 q = *(const f32x4*)(na + (long)dstn[eg] * 64 + ic * 4);
          ax[eg][0] = q[0]; ax[eg][1] = q[1]; ax[eg][2] = q[2]; ax[eg][3] = q[3];
        }
      } else {
#pragma unroll
        for (int eg = 0; eg < 4; eg++) {
          const float* nb = na + (long)dstn[eg] * 64 + 16 + ic * 12;
          f32x4 q0 = *(const f32x4*)(nb);
          f32x4 q1 = *(const f32x4*)(nb + 4);
          f32x4 q2 = *(const f32x4*)(nb + 8);
#pragma unroll
          for (int q = 0; q < 4; q++) { axv[eg][q] = q0[q]; axv[eg][4 + q] = q1[q]; axv[eg][8 + q] = q2[q]; }
        }
      }
#pragma unroll
      for (int ii = 0; ii < 4; ii++) {
        const int i = ic * 4 + ii;
        bf16x8 af0, af1;
        {
          int rc = i * 16 + l15;
          int x = (rc & 7) << 4;
          af0 = *(const bf16x8*)((char*)w2ld + rc * 128 + ((rg << 4) ^ x));
          af1 = *(const bf16x8*)((char*)w2ld + rc * 128 + (((4 + rg) << 4) ^ x));
        }
        f32x4 dinit = *(const f32x4*)(b2 + t * 256 + i * 16 + rg * 4);
        f32x4 d[4];
#pragma unroll
        for (int eg = 0; eg < 4; eg++) {
          d[eg] = __builtin_amdgcn_mfma_f32_16x16x32_bf16(af0, bfr[eg][0], dinit, 0, 0, 0);
          d[eg] = __builtin_amdgcn_mfma_f32_16x16x32_bf16(af1, bfr[eg][1], d[eg], 0, 0, 0);
        }
        if (t == 0) {
#pragma unroll
          for (int eg = 0; eg < 4; eg++) {
            float a = ax[eg][ii] * ss[eg];
#pragma unroll
            for (int r = 0; r < 4; r++) outs[eg][r] += a * d[eg][r];
          }
        } else if (t == 1) {
#pragma unroll
          for (int eg = 0; eg < 4; eg++) {
            float a = SQ3 * (axv[eg][3 * ii] * sv[eg][0] + axv[eg][3 * ii + 1] * sv[eg][1] +
                             axv[eg][3 * ii + 2] * sv[eg][2]);
#pragma unroll
            for (int r = 0; r < 4; r++) outs[eg][r] += a * d[eg][r];
          }
        } else if (t == 2) {
#pragma unroll
          for (int eg = 0; eg < 4; eg++) {
            float a = ax[eg][ii];
#pragma unroll
            for (int r = 0; r < 4; r++) tsv[eg][r] += a * d[eg][r];
          }
        } else {
#pragma unroll
          for (int eg = 0; eg < 4; eg++) {
            float a0 = SQ3 * ss[eg] * axv[eg][3 * ii];
            float a1 = SQ3 * ss[eg] * axv[eg][3 * ii + 1];
            float a2 = SQ3 * ss[eg] * axv[eg][3 * ii + 2];
#pragma unroll
            for (int r = 0; r < 4; r++) {
              outv[eg][r][0] += a0 * d[eg][r];
              outv[eg][r][1] += a1 * d[eg][r];
              outv[eg][r][2] += a2 * d[eg][r];
            }
          }
        }
      }
    }
    if (t == 2) {
#pragma unroll
      for (int eg = 0; eg < 4; eg++)
#pragma unroll
        for (int r = 0; r < 4; r++) {
          outv[eg][r][0] += SQ3 * tsv[eg][r] * sv[eg][0];
          outv[eg][r][1] += SQ3 * tsv[eg][r] * sv[eg][1];
          outv[eg][r][2] += SQ3 * tsv[eg][r] * sv[eg][2];
        }
    }
  }

  // scatter: tp = [out_s(16) | out_v(k,m) -> col 16+3k+m]
#pragma unroll 1
  for (int eg = 0; eg < 4; eg++) {
    if (!vld[eg]) continue;
    float* arow = agg + (long)srcn[eg] * 64;
    int kb = rg * 4;
#pragma unroll
    for (int r = 0; r < 4; r++) {
      unsafeAtomicAdd(arow + kb + r, ALPHAC * outs[eg][r]);
      unsafeAtomicAdd(arow + 16 + 3 * (kb + r) + 0, ALPHAC * outv[eg][r][0]);
      unsafeAtomicAdd(arow + 16 + 3 * (kb + r) + 1, ALPHAC * outv[eg][r][1]);
      unsafeAtomicAdd(arow + 16 + 3 * (kb + r) + 2, ALPHAC * outv[eg][r][2]);
    }
    if (rg == 0) unsafeAtomicAdd(cnt + srcn[eg], 1.0f);
  }
}

// ---------------------------------------------------------------------------
// K3: out_pre = agg/max(cnt,1) + node_attr (in-place into agg) + stat partials
// stats[0..63] = per-col sum, stats[64..127] = per-col sum of squares
// ---------------------------------------------------------------------------
__global__ __launch_bounds__(256) void k_norm1(
    float* __restrict__ agg, const float* __restrict__ cnt,
    const float* __restrict__ na, float* __restrict__ stats) {
  const int tid = threadIdx.x;
  const int lq = tid & 15, nsub = tid >> 4;
  const int c0 = lq * 4;
  float sum[4] = {0.f, 0.f, 0.f, 0.f}, sq[4] = {0.f, 0.f, 0.f, 0.f};
  for (int chunk = blockIdx.x; chunk < N_NODES / 16; chunk += gridDim.x) {
    long n = (long)chunk * 16 + nsub;
    float inv = 1.0f / fmaxf(cnt[n], 1.0f);
    f32x4 a = *(f32x4*)(agg + n * 64 + c0);
    f32x4 x = *(const f32x4*)(na + n * 64 + c0);
    f32x4 p;
#pragma unroll
    for (int j = 0; j < 4; j++) {
      p[j] = a[j] * inv + x[j];
      sum[j] += p[j];
      sq[j] += p[j] * p[j];
    }
    *(f32x4*)(agg + n * 64 + c0) = p;
  }
  __shared__ float csum[64], csq[64];
  if (tid < 64) { csum[tid] = 0.f; csq[tid] = 0.f; }
  __syncthreads();
#pragma unroll
  for (int j = 0; j < 4; j++) {
    atomicAdd(&csum[c0 + j], sum[j]);
    atomicAdd(&csq[c0 + j], sq[j]);
  }
  __syncthreads();
  if (tid < 64) {
    unsafeAtomicAdd(stats + tid, csum[tid]);
    unsafeAtomicAdd(stats + 64 + tid, csq[tid]);
  }
}

// ---------------------------------------------------------------------------
// K4: finalize batch-norm and write output
// ---------------------------------------------------------------------------
__global__ __launch_bounds__(256) void k_norm2(
    const float* __restrict__ agg, const float* __restrict__ stats,
    const float* __restrict__ bnw, const float* __restrict__ bnb,
    float* __restrict__ out) {
  const int tid = threadIdx.x;
  const int lq = tid & 15, nsub = tid >> 4;
  const int c0 = lq * 4;
  float sc[4], bi[4];
#pragma unroll
  for (int j = 0; j < 4; j++) {
    int c = c0 + j;
    if (c < 16) {
      float mean = stats[c] * (1.0f / N_NODES);
      float var = stats[64 + c] * (1.0f / N_NODES) - mean * mean;
      float rstd = rsqrtf(var + EPSC);
      sc[j] = rstd * bnw[c];
      bi[j] = bnb[c] - mean * rstd * bnw[c];
    } else {
      int k = (c - 16) / 3;
      float fn = (stats[64 + 16 + 3 * k] + stats[64 + 17 + 3 * k] + stats[64 + 18 + 3 * k]) *
                 (1.0f / (3.0f * N_NODES));
      sc[j] = rsqrtf(fn + EPSC) * bnw[16 + k];
      bi[j] = 0.f;
    }
  }
  for (int chunk = blockIdx.x; chunk < N_NODES / 16; chunk += gridDim.x) {
    long n = (long)chunk * 16 + nsub;
    f32x4 p = *(const f32x4*)(agg + n * 64 + c0);
    f32x4 o;
#pragma unroll
    for (int j = 0; j < 4; j++) o[j] = p[j] * sc[j] + bi[j];
    *(f32x4*)(out + n * 64 + c0) = o;
  }
}

// ---------------------------------------------------------------------------
extern "C" void kernel_launch(void* const* d_in, const int* in_sizes, int n_in,
                              void* d_out, int out_size, void* d_ws, size_t ws_size,
                              hipStream_t stream) {
  const float* na  = (const float*)d_in[0];
  const float* ea  = (const float*)d_in[1];
  const float* sh  = (const float*)d_in[2];
  const float* w1  = (const float*)d_in[3];
  const float* b1  = (const float*)d_in[4];
  const float* w2  = (const float*)d_in[5];
  const float* b2  = (const float*)d_in[6];
  const float* bnw = (const float*)d_in[7];
  const float* bnb = (const float*)d_in[8];
  const int*   ei  = (const int*)d_in[9];

  char* ws = (char*)d_ws;
  float* agg            = (float*)ws;                       // 12,800,000 B
  float* cnt            = (float*)(ws + 12800000);          //    200,000 B
  float* stats          = (float*)(ws + 13000000);          //        512 B
  unsigned short* hbf   = (unsigned short*)(ws + 13000512); // 25,600,000 B
  unsigned short* w1T   = (unsigned short*)(ws + 38600512); //      8,192 B
  unsigned short* w2T   = (unsigned short*)(ws + 38608704); //    131,072 B
  if (ws_size < 38739776) return;  // fail visibly (output stays poisoned)

  hipMemsetAsync(ws, 0, 13000512, stream);  // agg + cnt + stats
  hipLaunchKernelGGL(k_convert, dim3(256), dim3(256), 0, stream, w1, w2, w1T, w2T);
  hipLaunchKernelGGL(k_gemm1, dim3(391), dim3(256), 0, stream, ea, w1T, b1, hbf);
  hipLaunchKernelGGL(k_fused, dim3(782), dim3(256), 0, stream, hbf, w2T, b2, na, sh, ei, agg, cnt);
  hipLaunchKernelGGL(k_norm1, dim3(512), dim3(256), 0, stream, agg, cnt, na, stats);
  hipLaunchKernelGGL(k_norm2, dim3(512), dim3(256), 0, stream, agg, stats, bnw, bnb, (float*)d_out);
}

// Round 3
// 1059.062 us; speedup vs baseline: 1.1868x; 1.1868x over previous
//
#include <hip/hip_runtime.h>
#include <stdint.h>

#define N_NODES 50000
#define N_EDGES 200000
#define SQ3 0.5773502691896258f
#define ALPHAC 0.17677669529663687f
#define EPSC 1e-5f
#define FXS 1048576.f          // 2^20 fixed-point scale
#define FXI (1.f / 1048576.f)

typedef unsigned short u16;
typedef unsigned long long u64;
typedef __attribute__((ext_vector_type(8))) __bf16 bf16x8;
typedef __attribute__((ext_vector_type(4))) float f32x4;
typedef __attribute__((ext_vector_type(4))) unsigned int u32x4;
typedef __attribute__((ext_vector_type(2))) unsigned int u32x2;

static __device__ __forceinline__ u16 bf16_rne(float f) {
  union { float f; unsigned int u; } v; v.f = f;
  return (u16)((v.u + 0x7fffu + ((v.u >> 16) & 1u)) >> 16);
}
static __device__ __forceinline__ float bf2f(u16 h) {
  union { unsigned int u; float f; } v; v.u = ((unsigned int)h) << 16;
  return v.f;
}
static __device__ __forceinline__ unsigned int pack2(float a, float b) {
  return (unsigned int)bf16_rne(a) | ((unsigned int)bf16_rne(b) << 16);
}

// ---------------------------------------------------------------------------
// K0: weight transpose+hi/lo-split to bf16, plus src-degree histogram.
// ---------------------------------------------------------------------------
__global__ __launch_bounds__(256) void k_prep(
    const float* __restrict__ w1, const float* __restrict__ w2, const int* __restrict__ ei,
    u16* __restrict__ w1h, u16* __restrict__ w1l,
    u16* __restrict__ w2h, u16* __restrict__ w2l, int* __restrict__ deg) {
  int idx = blockIdx.x * 256 + threadIdx.x;
  if (idx < 64 * 64) {
    int c = idx >> 6, j = idx & 63;
    float x = w1[j * 64 + c];
    u16 h = bf16_rne(x);
    w1h[idx] = h; w1l[idx] = bf16_rne(x - bf2f(h));
  }
  if (idx < 1024 * 64) {
    int c = idx >> 6, j = idx & 63;
    float x = w2[j * 1024 + c];
    u16 h = bf16_rne(x);
    w2h[idx] = h; w2l[idx] = bf16_rne(x - bf2f(h));
  }
  if (idx < N_EDGES) atomicAdd(&deg[ei[idx]], 1);
}

// ---------------------------------------------------------------------------
// K1a: per-256-bin-block intra scan (exclusive) -> off/cursor, block totals
// ---------------------------------------------------------------------------
__global__ __launch_bounds__(256) void k_scan1(
    const int* __restrict__ deg, int* __restrict__ off, int* __restrict__ cursor,
    int* __restrict__ bsum) {
  __shared__ int part[256];
  int t = threadIdx.x;
  int b = blockIdx.x * 256 + t;
  int v = (b < N_NODES) ? deg[b] : 0;
  part[t] = v;
  __syncthreads();
  for (int d = 1; d < 256; d <<= 1) {
    int add = (t >= d) ? part[t - d] : 0;
    __syncthreads();
    part[t] += add;
    __syncthreads();
  }
  int excl = part[t] - v;
  if (b <= N_NODES) off[b] = excl;
  if (b < N_NODES) cursor[b] = excl;
  if (t == 255) bsum[blockIdx.x] = part[255];
}

__global__ __launch_bounds__(256) void k_scan2(const int* __restrict__ bsum, int* __restrict__ bpre) {
  __shared__ int part[256];
  int t = threadIdx.x;
  int v = (t < 196) ? bsum[t] : 0;
  part[t] = v;
  __syncthreads();
  for (int d = 1; d < 256; d <<= 1) {
    int add = (t >= d) ? part[t - d] : 0;
    __syncthreads();
    part[t] += add;
    __syncthreads();
  }
  if (t < 196) bpre[t] = part[t] - v;
}

__global__ __launch_bounds__(256) void k_fill(
    const int* __restrict__ ei, int* __restrict__ cursor, const int* __restrict__ bpre,
    int* __restrict__ pos) {
  int e = blockIdx.x * 256 + threadIdx.x;
  if (e < N_EDGES) {
    int s = ei[e];
    pos[e] = atomicAdd(&cursor[s], 1) + bpre[s >> 8];
  }
}

// ---------------------------------------------------------------------------
// K2: fused GEMM1 (hi/lo) -> LDS bounce -> GEMM2 (hi/lo, LDS-staged w2,
// XOR-swizzled) -> tensor-product -> bf16 tp row at sorted position.
// Per-edge deterministic; positions may permute run-to-run (k_agg is
// order-independent so that's fine).
// ---------------------------------------------------------------------------
__global__ __launch_bounds__(256, 2) void k_fused(
    const float* __restrict__ ea, const float* __restrict__ b1, const float* __restrict__ b2,
    const float* __restrict__ na, const float* __restrict__ sh, const int* __restrict__ ei,
    const int* __restrict__ pos,
    const u16* __restrict__ w1h, const u16* __restrict__ w1l,
    const u16* __restrict__ w2h, const u16* __restrict__ w2l,
    u16* __restrict__ tp) {
  __shared__ u16 w1ld[128 * 64];   // 16 KB: rows 0..63 w1 hi, 64..127 w1 lo (swizzled)
  __shared__ char smem[65536];     // prologue: 4x16KB per-wave bounce; main: 32KB w2 chunk
  u16* w2ld = (u16*)smem;

  const int tid = threadIdx.x;
  const int lane = tid & 63;
  const int wid = tid >> 6;
  const int l15 = lane & 15, rg = lane >> 4;
  const int x7 = l15 & 7;
  unsigned int* bounce = (unsigned int*)(smem + wid * 16384);

#pragma unroll
  for (int it = 0; it < 4; it++) {
    int s = it * 256 + tid;
    int rc = s >> 3, sl = s & 7;
    const u16* src = (rc < 64) ? (w1h + rc * 64) : (w1l + (rc - 64) * 64);
    u32x4 v = *(const u32x4*)(src + sl * 8);
    *(u32x4*)((char*)w1ld + rc * 128 + ((sl ^ (rc & 7)) << 4)) = v;
  }
  __syncthreads();

  const long eb_wave = (long)blockIdx.x * 256 + wid * 64;

  int dstn[4], posv[4], vld[4];
  float ss[4], sv0[4], sv1[4], sv2[4];
  bf16x8 hh[4][2], hl[4][2];

  f32x4 binit[4];
#pragma unroll
  for (int cf = 0; cf < 4; cf++) binit[cf] = *(const f32x4*)(b1 + cf * 16 + rg * 4);

#pragma unroll
  for (int eg = 0; eg < 4; eg++) {
    long ebase = eb_wave + eg * 16;
    vld[eg] = (ebase < N_EDGES);
    long e = vld[eg] ? (ebase + l15) : (long)l15;
    dstn[eg] = ei[N_EDGES + e];
    posv[eg] = pos[e];
    f32x4 s4 = *(const f32x4*)(sh + e * 4);
    ss[eg] = s4[0]; sv0[eg] = s4[1]; sv1[eg] = s4[2]; sv2[eg] = s4[3];

    bf16x8 ehi[2], elo[2];
#pragma unroll
    for (int ks = 0; ks < 2; ks++) {
      const float* rp = ea + e * 64 + ks * 32 + rg * 8;
      f32x4 q0 = *(const f32x4*)(rp);
      f32x4 q1 = *(const f32x4*)(rp + 4);
      union { u16 u[8]; bf16x8 v; } ph, pl;
      float xs8[8] = {q0[0], q0[1], q0[2], q0[3], q1[0], q1[1], q1[2], q1[3]};
#pragma unroll
      for (int j = 0; j < 8; j++) {
        u16 h = bf16_rne(xs8[j]);
        ph.u[j] = h;
        pl.u[j] = bf16_rne(xs8[j] - bf2f(h));
      }
      ehi[ks] = ph.v; elo[ks] = pl.v;
    }

#pragma unroll
    for (int cf = 0; cf < 4; cf++) {
      const char* bh = (char*)w1ld + (cf * 16 + l15) * 128;
      const char* bl = bh + 64 * 128;
      bf16x8 ah0 = *(const bf16x8*)(bh + ((rg ^ x7) << 4));
      bf16x8 ah1 = *(const bf16x8*)(bh + (((4 + rg) ^ x7) << 4));
      bf16x8 al0 = *(const bf16x8*)(bl + ((rg ^ x7) << 4));
      bf16x8 al1 = *(const bf16x8*)(bl + (((4 + rg) ^ x7) << 4));
      f32x4 d = binit[cf];
      d = __builtin_amdgcn_mfma_f32_16x16x32_bf16(ah0, ehi[0], d, 0, 0, 0);
      d = __builtin_amdgcn_mfma_f32_16x16x32_bf16(ah1, ehi[1], d, 0, 0, 0);
      d = __builtin_amdgcn_mfma_f32_16x16x32_bf16(al0, ehi[0], d, 0, 0, 0);
      d = __builtin_amdgcn_mfma_f32_16x16x32_bf16(al1, ehi[1], d, 0, 0, 0);
      d = __builtin_amdgcn_mfma_f32_16x16x32_bf16(ah0, elo[0], d, 0, 0, 0);
      d = __builtin_amdgcn_mfma_f32_16x16x32_bf16(ah1, elo[1], d, 0, 0, 0);
      u32x4 pk;
#pragma unroll
      for (int r = 0; r < 4; r++) {
        float hv = fmaxf(d[r], 0.f);
        u16 hi = bf16_rne(hv);
        u16 lo = bf16_rne(hv - bf2f(hi));
        pk[r] = (unsigned int)hi | ((unsigned int)lo << 16);
      }
      int slot = (cf * 4 + rg) ^ l15;
      *(u32x4*)((char*)bounce + (eg * 16 + l15) * 256 + (slot << 4)) = pk;
    }
#pragma unroll
    for (int ks = 0; ks < 2; ks++) {
      int s0 = (ks * 8 + rg * 2) ^ l15;
      int s1 = (ks * 8 + rg * 2 + 1) ^ l15;
      u32x4 a = *(const u32x4*)((char*)bounce + (eg * 16 + l15) * 256 + (s0 << 4));
      u32x4 b = *(const u32x4*)((char*)bounce + (eg * 16 + l15) * 256 + (s1 << 4));
      union { u16 u[8]; bf16x8 v; } ph, pl;
#pragma unroll
      for (int j = 0; j < 4; j++) {
        ph.u[j] = (u16)(a[j] & 0xffff);     pl.u[j] = (u16)(a[j] >> 16);
        ph.u[4 + j] = (u16)(b[j] & 0xffff); pl.u[4 + j] = (u16)(b[j] >> 16);
      }
      hh[eg][ks] = ph.v; hl[eg][ks] = pl.v;
    }
  }

  float outs[4][4], outv[4][4][3], tsv[4][4];
#pragma unroll
  for (int eg = 0; eg < 4; eg++)
#pragma unroll
    for (int r = 0; r < 4; r++) {
      outs[eg][r] = 0.f; tsv[eg][r] = 0.f;
      outv[eg][r][0] = 0.f; outv[eg][r][1] = 0.f; outv[eg][r][2] = 0.f;
    }

#pragma unroll 1
  for (int tc = 0; tc < 8; tc++) {
    __syncthreads();
#pragma unroll
    for (int it = 0; it < 8; it++) {
      int s = it * 256 + tid;
      int rc = s >> 3, sl = s & 7;
      const u16* src = (rc < 128) ? (w2h + (long)(tc * 128 + rc) * 64)
                                  : (w2l + (long)(tc * 128 + rc - 128) * 64);
      u32x4 v = *(const u32x4*)(src + sl * 8);
      *(u32x4*)((char*)w2ld + rc * 128 + ((sl ^ (rc & 7)) << 4)) = v;
    }
    __syncthreads();

    const int t = tc >> 1;
    const int ibase = (tc & 1) * 8;
#pragma unroll 1
    for (int ih = 0; ih < 2; ih++) {
      float ax[4][4], axv[4][12];
      if (t == 0 || t == 2) {
        int coff = ibase + ih * 4;
#pragma unroll
        for (int eg = 0; eg < 4; eg++) {
          f32x4 q = *(const f32x4*)(na + (long)dstn[eg] * 64 + coff);
          ax[eg][0] = q[0]; ax[eg][1] = q[1]; ax[eg][2] = q[2]; ax[eg][3] = q[3];
        }
      } else {
        int base3 = (ibase + ih * 4) * 3;
#pragma unroll
        for (int eg = 0; eg < 4; eg++) {
          const float* nb = na + (long)dstn[eg] * 64 + 16 + base3;
          f32x4 q0 = *(const f32x4*)(nb);
          f32x4 q1 = *(const f32x4*)(nb + 4);
          f32x4 q2 = *(const f32x4*)(nb + 8);
#pragma unroll
          for (int q = 0; q < 4; q++) {
            axv[eg][q] = q0[q]; axv[eg][4 + q] = q1[q]; axv[eg][8 + q] = q2[q];
          }
        }
      }
#pragma unroll
      for (int iw = 0; iw < 4; iw++) {
        const int il = ih * 4 + iw;
        const char* bh = (char*)w2ld + (il * 16 + l15) * 128;
        const char* bl = bh + 128 * 128;
        bf16x8 wh0 = *(const bf16x8*)(bh + ((rg ^ x7) << 4));
        bf16x8 wh1 = *(const bf16x8*)(bh + (((4 + rg) ^ x7) << 4));
        bf16x8 wl0 = *(const bf16x8*)(bl + ((rg ^ x7) << 4));
        bf16x8 wl1 = *(const bf16x8*)(bl + (((4 + rg) ^ x7) << 4));
        f32x4 dinit = *(const f32x4*)(b2 + (tc * 8 + il) * 16 + rg * 4);
        f32x4 d[4];
#pragma unroll
        for (int eg = 0; eg < 4; eg++) {
          f32x4 acc = dinit;
          acc = __builtin_amdgcn_mfma_f32_16x16x32_bf16(wh0, hh[eg][0], acc, 0, 0, 0);
          acc = __builtin_amdgcn_mfma_f32_16x16x32_bf16(wh1, hh[eg][1], acc, 0, 0, 0);
          acc = __builtin_amdgcn_mfma_f32_16x16x32_bf16(wl0, hh[eg][0], acc, 0, 0, 0);
          acc = __builtin_amdgcn_mfma_f32_16x16x32_bf16(wl1, hh[eg][1], acc, 0, 0, 0);
          acc = __builtin_amdgcn_mfma_f32_16x16x32_bf16(wh0, hl[eg][0], acc, 0, 0, 0);
          acc = __builtin_amdgcn_mfma_f32_16x16x32_bf16(wh1, hl[eg][1], acc, 0, 0, 0);
          d[eg] = acc;
        }
        if (t == 0) {
#pragma unroll
          for (int eg = 0; eg < 4; eg++) {
            float a = ax[eg][iw] * ss[eg];
#pragma unroll
            for (int r = 0; r < 4; r++) outs[eg][r] += a * d[eg][r];
          }
        } else if (t == 1) {
#pragma unroll
          for (int eg = 0; eg < 4; eg++) {
            float a = SQ3 * (axv[eg][3 * iw] * sv0[eg] + axv[eg][3 * iw + 1] * sv1[eg] +
                             axv[eg][3 * iw + 2] * sv2[eg]);
#pragma unroll
            for (int r = 0; r < 4; r++) outs[eg][r] += a * d[eg][r];
          }
        } else if (t == 2) {
#pragma unroll
          for (int eg = 0; eg < 4; eg++) {
            float a = ax[eg][iw];
#pragma unroll
            for (int r = 0; r < 4; r++) tsv[eg][r] += a * d[eg][r];
          }
        } else {
#pragma unroll
          for (int eg = 0; eg < 4; eg++) {
            float a0 = SQ3 * ss[eg] * axv[eg][3 * iw];
            float a1 = SQ3 * ss[eg] * axv[eg][3 * iw + 1];
            float a2 = SQ3 * ss[eg] * axv[eg][3 * iw + 2];
#pragma unroll
            for (int r = 0; r < 4; r++) {
              outv[eg][r][0] += a0 * d[eg][r];
              outv[eg][r][1] += a1 * d[eg][r];
              outv[eg][r][2] += a2 * d[eg][r];
            }
          }
        }
      }
    }
  }

#pragma unroll
  for (int eg = 0; eg < 4; eg++)
#pragma unroll
    for (int r = 0; r < 4; r++) {
      outv[eg][r][0] += SQ3 * tsv[eg][r] * sv0[eg];
      outv[eg][r][1] += SQ3 * tsv[eg][r] * sv1[eg];
      outv[eg][r][2] += SQ3 * tsv[eg][r] * sv2[eg];
    }

#pragma unroll
  for (int eg = 0; eg < 4; eg++) {
    if (!vld[eg]) continue;
    char* row = (char*)(tp + (long)posv[eg] * 64);
    int kb = rg * 4;
    u32x2 w0;
    w0[0] = pack2(ALPHAC * outs[eg][0], ALPHAC * outs[eg][1]);
    w0[1] = pack2(ALPHAC * outs[eg][2], ALPHAC * outs[eg][3]);
    *(u32x2*)(row + kb * 2) = w0;
    u32x2 w1v, w2v, w3v;
    w1v[0] = pack2(ALPHAC * outv[eg][0][0], ALPHAC * outv[eg][0][1]);
    w1v[1] = pack2(ALPHAC * outv[eg][0][2], ALPHAC * outv[eg][1][0]);
    w2v[0] = pack2(ALPHAC * outv[eg][1][1], ALPHAC * outv[eg][1][2]);
    w2v[1] = pack2(ALPHAC * outv[eg][2][0], ALPHAC * outv[eg][2][1]);
    w3v[0] = pack2(ALPHAC * outv[eg][2][2], ALPHAC * outv[eg][3][0]);
    w3v[1] = pack2(ALPHAC * outv[eg][3][1], ALPHAC * outv[eg][3][2]);
    *(u32x2*)(row + (16 + 3 * kb) * 2) = w1v;
    *(u32x2*)(row + (16 + 3 * kb) * 2 + 8) = w2v;
    *(u32x2*)(row + (16 + 3 * kb) * 2 + 16) = w3v;
  }
}

// ---------------------------------------------------------------------------
// K3: order-independent segment sum (int64 fixed-point, exact) -> mean ->
// +node_attr -> d_out; BN stat partials via fixed-order LDS tree + int64
// global atomics (associative => deterministic).
// ---------------------------------------------------------------------------
__global__ __launch_bounds__(256) void k_agg(
    const u16* __restrict__ tp, const int* __restrict__ off, const int* __restrict__ bpre,
    const float* __restrict__ na, float* __restrict__ outp, u64* __restrict__ stats) {
  const int tid = threadIdx.x;
  const int lq = tid & 15, grp = tid >> 4;
  const int c0 = lq * 4;
  float sum4[4] = {0.f, 0.f, 0.f, 0.f}, sq4[4] = {0.f, 0.f, 0.f, 0.f};
  for (int chunk = blockIdx.x; chunk < N_NODES / 16; chunk += gridDim.x) {
    int n = chunk * 16 + grp;
    int o0 = off[n] + bpre[n >> 8];
    int o1 = off[n + 1] + bpre[(n + 1) >> 8];
    long long acc[4] = {0, 0, 0, 0};
    for (int r = o0; r < o1; r++) {
      u32x2 v = *(const u32x2*)(tp + (long)r * 64 + c0);
      acc[0] += (long long)rintf(bf2f((u16)(v[0] & 0xffff)) * FXS);
      acc[1] += (long long)rintf(bf2f((u16)(v[0] >> 16)) * FXS);
      acc[2] += (long long)rintf(bf2f((u16)(v[1] & 0xffff)) * FXS);
      acc[3] += (long long)rintf(bf2f((u16)(v[1] >> 16)) * FXS);
    }
    float inv = 1.0f / fmaxf((float)(o1 - o0), 1.0f);
    f32x4 x = *(const f32x4*)(na + (long)n * 64 + c0);
    f32x4 p;
#pragma unroll
    for (int j = 0; j < 4; j++) {
      float a = (float)acc[j] * FXI;
      p[j] = a * inv + x[j];
      sum4[j] += p[j];
      sq4[j] += p[j] * p[j];
    }
    *(f32x4*)(outp + (long)n * 64 + c0) = p;
  }
  __shared__ float psum[16][64], psq[16][64];
  *(f32x4*)&psum[grp][c0] = (f32x4){sum4[0], sum4[1], sum4[2], sum4[3]};
  *(f32x4*)&psq[grp][c0]  = (f32x4){sq4[0], sq4[1], sq4[2], sq4[3]};
  __syncthreads();
  if (tid < 64) {
    float ts = 0.f, tq = 0.f;
    for (int g = 0; g < 16; g++) { ts += psum[g][tid]; tq += psq[g][tid]; }
    atomicAdd(&stats[tid], (u64)(long long)rintf(ts * FXS));
    atomicAdd(&stats[64 + tid], (u64)(long long)rintf(tq * FXS));
  }
}

// ---------------------------------------------------------------------------
// K4: finalize batch-norm (stats from int64 fixed-point), in place on d_out
// ---------------------------------------------------------------------------
__global__ __launch_bounds__(256) void k_norm2(
    const float* __restrict__ inp, const u64* __restrict__ stats,
    const float* __restrict__ bnw, const float* __restrict__ bnb,
    float* __restrict__ out) {
  const int tid = threadIdx.x;
  const int lq = tid & 15, nsub = tid >> 4;
  const int c0 = lq * 4;
  float sc[4], bi[4];
#pragma unroll
  for (int j = 0; j < 4; j++) {
    int c = c0 + j;
    float sumc = (float)((double)(long long)stats[c] * (1.0 / 1048576.0));
    float sqc  = (float)((double)(long long)stats[64 + c] * (1.0 / 1048576.0));
    if (c < 16) {
      float mean = sumc * (1.0f / N_NODES);
      float var = sqc * (1.0f / N_NODES) - mean * mean;
      float rstd = rsqrtf(var + EPSC);
      sc[j] = rstd * bnw[c];
      bi[j] = bnb[c] - mean * rstd * bnw[c];
    } else {
      int k = (c - 16) / 3;
      float q0 = (float)((double)(long long)stats[64 + 16 + 3 * k] * (1.0 / 1048576.0));
      float q1 = (float)((double)(long long)stats[64 + 17 + 3 * k] * (1.0 / 1048576.0));
      float q2 = (float)((double)(long long)stats[64 + 18 + 3 * k] * (1.0 / 1048576.0));
      float fn = (q0 + q1 + q2) * (1.0f / (3.0f * N_NODES));
      sc[j] = rsqrtf(fn + EPSC) * bnw[16 + k];
      bi[j] = 0.f;
    }
  }
  for (int chunk = blockIdx.x; chunk < N_NODES / 16; chunk += gridDim.x) {
    long n = (long)chunk * 16 + nsub;
    f32x4 p = *(const f32x4*)(inp + n * 64 + c0);
    f32x4 o;
#pragma unroll
    for (int j = 0; j < 4; j++) o[j] = p[j] * sc[j] + bi[j];
    *(f32x4*)(out + n * 64 + c0) = o;
  }
}

// ---------------------------------------------------------------------------
extern "C" void kernel_launch(void* const* d_in, const int* in_sizes, int n_in,
                              void* d_out, int out_size, void* d_ws, size_t ws_size,
                              hipStream_t stream) {
  const float* na  = (const float*)d_in[0];
  const float* ea  = (const float*)d_in[1];
  const float* sh  = (const float*)d_in[2];
  const float* w1  = (const float*)d_in[3];
  const float* b1  = (const float*)d_in[4];
  const float* w2  = (const float*)d_in[5];
  const float* b2  = (const float*)d_in[6];
  const float* bnw = (const float*)d_in[7];
  const float* bnb = (const float*)d_in[8];
  const int*   ei  = (const int*)d_in[9];

  char* ws = (char*)d_ws;
  u16*   tp     = (u16*)ws;                     // 25,600,000
  int*   pos    = (int*)(ws + 25600000);        //    800,000
  int*   off    = (int*)(ws + 26400000);        //    200,064 (N+1 ints)
  int*   cursor = (int*)(ws + 26600064);        //    200,064
  int*   deg    = (int*)(ws + 26800128);        //    200,000
  u64*   stats  = (u64*)(ws + 27000128);        //      1,024 (ll[128])
  u16*   w1h    = (u16*)(ws + 27001152);        //      8,192
  u16*   w1l    = (u16*)(ws + 27009344);        //      8,192
  u16*   w2h    = (u16*)(ws + 27017536);        //    131,072
  u16*   w2l    = (u16*)(ws + 27148608);        //    131,072
  int*   bsum   = (int*)(ws + 27279680);        //      1,024
  int*   bpre   = (int*)(ws + 27280704);        //      1,024
  if (ws_size < 27281728) return;  // fail visibly (output stays poisoned)

  hipMemsetAsync(ws + 26800128, 0, 201024, stream);  // deg + stats
  hipLaunchKernelGGL(k_prep,  dim3(782), dim3(256), 0, stream, w1, w2, ei, w1h, w1l, w2h, w2l, deg);
  hipLaunchKernelGGL(k_scan1, dim3(196), dim3(256), 0, stream, deg, off, cursor, bsum);
  hipLaunchKernelGGL(k_scan2, dim3(1),   dim3(256), 0, stream, bsum, bpre);
  hipLaunchKernelGGL(k_fill,  dim3(782), dim3(256), 0, stream, ei, cursor, bpre, pos);
  hipLaunchKernelGGL(k_fused, dim3(782), dim3(256), 0, stream,
                     ea, b1, b2, na, sh, ei, pos, w1h, w1l, w2h, w2l, tp);
  hipLaunchKernelGGL(k_agg,   dim3(512), dim3(256), 0, stream, tp, off, bpre, na, (float*)d_out, stats);
  hipLaunchKernelGGL(k_norm2, dim3(512), dim3(256), 0, stream, (float*)d_out, stats, bnw, bnb, (float*)d_out);
}

// Round 4
// 355.479 us; speedup vs baseline: 3.5358x; 2.9793x over previous
//
#include <hip/hip_runtime.h>
#include <stdint.h>

#define N_NODES 50000
#define N_EDGES 200000
#define SQ3 0.5773502691896258f
#define ALPHAC 0.17677669529663687f
#define EPSC 1e-5f
#define FXS 1048576.f          // 2^20 fixed-point scale
#define FXI (1.f / 1048576.f)

typedef unsigned short u16;
typedef unsigned long long u64;
typedef __attribute__((ext_vector_type(8))) __bf16 bf16x8;
typedef __attribute__((ext_vector_type(4))) float f32x4;
typedef __attribute__((ext_vector_type(4))) unsigned int u32x4;
typedef __attribute__((ext_vector_type(2))) unsigned int u32x2;

static __device__ __forceinline__ u16 bf16_rne(float f) {
  union { float f; unsigned int u; } v; v.f = f;
  return (u16)((v.u + 0x7fffu + ((v.u >> 16) & 1u)) >> 16);
}
static __device__ __forceinline__ float bf2f(u16 h) {
  union { unsigned int u; float f; } v; v.u = ((unsigned int)h) << 16;
  return v.f;
}
static __device__ __forceinline__ unsigned int pack2(float a, float b) {
  return (unsigned int)bf16_rne(a) | ((unsigned int)bf16_rne(b) << 16);
}

// ---------------------------------------------------------------------------
// K0: weight transpose+hi/lo-split to bf16, plus src-degree histogram.
// ---------------------------------------------------------------------------
__global__ __launch_bounds__(256) void k_prep(
    const float* __restrict__ w1, const float* __restrict__ w2, const int* __restrict__ ei,
    u16* __restrict__ w1h, u16* __restrict__ w1l,
    u16* __restrict__ w2h, u16* __restrict__ w2l, int* __restrict__ deg) {
  int idx = blockIdx.x * 256 + threadIdx.x;
  if (idx < 64 * 64) {
    int c = idx >> 6, j = idx & 63;
    float x = w1[j * 64 + c];
    u16 h = bf16_rne(x);
    w1h[idx] = h; w1l[idx] = bf16_rne(x - bf2f(h));
  }
  if (idx < 1024 * 64) {
    int c = idx >> 6, j = idx & 63;
    float x = w2[j * 1024 + c];
    u16 h = bf16_rne(x);
    w2h[idx] = h; w2l[idx] = bf16_rne(x - bf2f(h));
  }
  if (idx < N_EDGES) atomicAdd(&deg[ei[idx]], 1);
}

// ---------------------------------------------------------------------------
// K1a/K1b/K1c: counting-sort position assignment (deterministic consumers)
// ---------------------------------------------------------------------------
__global__ __launch_bounds__(256) void k_scan1(
    const int* __restrict__ deg, int* __restrict__ off, int* __restrict__ cursor,
    int* __restrict__ bsum) {
  __shared__ int part[256];
  int t = threadIdx.x;
  int b = blockIdx.x * 256 + t;
  int v = (b < N_NODES) ? deg[b] : 0;
  part[t] = v;
  __syncthreads();
  for (int d = 1; d < 256; d <<= 1) {
    int add = (t >= d) ? part[t - d] : 0;
    __syncthreads();
    part[t] += add;
    __syncthreads();
  }
  int excl = part[t] - v;
  if (b <= N_NODES) off[b] = excl;
  if (b < N_NODES) cursor[b] = excl;
  if (t == 255) bsum[blockIdx.x] = part[255];
}

__global__ __launch_bounds__(256) void k_scan2(const int* __restrict__ bsum, int* __restrict__ bpre) {
  __shared__ int part[256];
  int t = threadIdx.x;
  int v = (t < 196) ? bsum[t] : 0;
  part[t] = v;
  __syncthreads();
  for (int d = 1; d < 256; d <<= 1) {
    int add = (t >= d) ? part[t - d] : 0;
    __syncthreads();
    part[t] += add;
    __syncthreads();
  }
  if (t < 196) bpre[t] = part[t] - v;
}

__global__ __launch_bounds__(256) void k_fill(
    const int* __restrict__ ei, int* __restrict__ cursor, const int* __restrict__ bpre,
    int* __restrict__ pos) {
  int e = blockIdx.x * 256 + threadIdx.x;
  if (e < N_EDGES) {
    int s = ei[e];
    pos[e] = atomicAdd(&cursor[s], 1) + bpre[s >> 8];
  }
}

// ---------------------------------------------------------------------------
// K2: fused GEMM1 (hi/lo) -> LDS bounce -> GEMM2 (hi/lo, LDS-staged w2,
// XOR-swizzled) -> tensor-product -> bf16 tp row at sorted position.
// EG=2 (32 edges/wave): keeps live VGPR state ~170 => no scratch spill
// (round-3 EG=4 spilled ~1.9 GB and was 10x slower than its pipe work).
// ---------------------------------------------------------------------------
#define EG 2
__global__ __launch_bounds__(256, 2) void k_fused(
    const float* __restrict__ ea, const float* __restrict__ b1, const float* __restrict__ b2,
    const float* __restrict__ na, const float* __restrict__ sh, const int* __restrict__ ei,
    const int* __restrict__ pos,
    const u16* __restrict__ w1h, const u16* __restrict__ w1l,
    const u16* __restrict__ w2h, const u16* __restrict__ w2l,
    u16* __restrict__ tp) {
  __shared__ u16 w1ld[128 * 64];   // 16 KB: rows 0..63 w1 hi, 64..127 w1 lo (swizzled)
  __shared__ char smem[32768];     // prologue: 4 x 8KB per-wave bounce; main: 32KB w2 chunk
  u16* w2ld = (u16*)smem;

  const int tid = threadIdx.x;
  const int lane = tid & 63;
  const int wid = tid >> 6;
  const int l15 = lane & 15, rg = lane >> 4;
  const int x7 = l15 & 7;
  unsigned int* bounce = (unsigned int*)(smem + wid * 8192); // [32 rows][16 x 16B slots]

#pragma unroll
  for (int it = 0; it < 4; it++) {
    int s = it * 256 + tid;
    int rc = s >> 3, sl = s & 7;
    const u16* src = (rc < 64) ? (w1h + rc * 64) : (w1l + (rc - 64) * 64);
    u32x4 v = *(const u32x4*)(src + sl * 8);
    *(u32x4*)((char*)w1ld + rc * 128 + ((sl ^ (rc & 7)) << 4)) = v;
  }
  __syncthreads();

  const long eb_wave = (long)blockIdx.x * (64 * EG) + wid * (16 * EG);

  int dstn[EG], posv[EG], vld[EG];
  float ss[EG], sv0[EG], sv1[EG], sv2[EG];
  bf16x8 hh[EG][2], hl[EG][2];

  f32x4 binit[4];
#pragma unroll
  for (int cf = 0; cf < 4; cf++) binit[cf] = *(const f32x4*)(b1 + cf * 16 + rg * 4);

#pragma unroll
  for (int eg = 0; eg < EG; eg++) {
    long ebase = eb_wave + eg * 16;
    vld[eg] = (ebase < N_EDGES);
    long e = vld[eg] ? (ebase + l15) : (long)l15;
    dstn[eg] = ei[N_EDGES + e];
    posv[eg] = pos[e];
    f32x4 s4 = *(const f32x4*)(sh + e * 4);
    ss[eg] = s4[0]; sv0[eg] = s4[1]; sv1[eg] = s4[2]; sv2[eg] = s4[3];

    bf16x8 ehi[2], elo[2];
#pragma unroll
    for (int ks = 0; ks < 2; ks++) {
      const float* rp = ea + e * 64 + ks * 32 + rg * 8;
      f32x4 q0 = *(const f32x4*)(rp);
      f32x4 q1 = *(const f32x4*)(rp + 4);
      union { u16 u[8]; bf16x8 v; } ph, pl;
      float xs8[8] = {q0[0], q0[1], q0[2], q0[3], q1[0], q1[1], q1[2], q1[3]};
#pragma unroll
      for (int j = 0; j < 8; j++) {
        u16 h = bf16_rne(xs8[j]);
        ph.u[j] = h;
        pl.u[j] = bf16_rne(xs8[j] - bf2f(h));
      }
      ehi[ks] = ph.v; elo[ks] = pl.v;
    }

#pragma unroll
    for (int cf = 0; cf < 4; cf++) {
      const char* bh = (char*)w1ld + (cf * 16 + l15) * 128;
      const char* bl = bh + 64 * 128;
      bf16x8 ah0 = *(const bf16x8*)(bh + ((rg ^ x7) << 4));
      bf16x8 ah1 = *(const bf16x8*)(bh + (((4 + rg) ^ x7) << 4));
      bf16x8 al0 = *(const bf16x8*)(bl + ((rg ^ x7) << 4));
      bf16x8 al1 = *(const bf16x8*)(bl + (((4 + rg) ^ x7) << 4));
      f32x4 d = binit[cf];
      d = __builtin_amdgcn_mfma_f32_16x16x32_bf16(ah0, ehi[0], d, 0, 0, 0);
      d = __builtin_amdgcn_mfma_f32_16x16x32_bf16(ah1, ehi[1], d, 0, 0, 0);
      d = __builtin_amdgcn_mfma_f32_16x16x32_bf16(al0, ehi[0], d, 0, 0, 0);
      d = __builtin_amdgcn_mfma_f32_16x16x32_bf16(al1, ehi[1], d, 0, 0, 0);
      d = __builtin_amdgcn_mfma_f32_16x16x32_bf16(ah0, elo[0], d, 0, 0, 0);
      d = __builtin_amdgcn_mfma_f32_16x16x32_bf16(ah1, elo[1], d, 0, 0, 0);
      u32x4 pk;
#pragma unroll
      for (int r = 0; r < 4; r++) {
        float hv = fmaxf(d[r], 0.f);
        u16 hi = bf16_rne(hv);
        u16 lo = bf16_rne(hv - bf2f(hi));
        pk[r] = (unsigned int)hi | ((unsigned int)lo << 16);
      }
      int slot = (cf * 4 + rg) ^ l15;
      *(u32x4*)((char*)bounce + (eg * 16 + l15) * 256 + (slot << 4)) = pk;
    }
#pragma unroll
    for (int ks = 0; ks < 2; ks++) {
      int s0 = (ks * 8 + rg * 2) ^ l15;
      int s1 = (ks * 8 + rg * 2 + 1) ^ l15;
      u32x4 a = *(const u32x4*)((char*)bounce + (eg * 16 + l15) * 256 + (s0 << 4));
      u32x4 b = *(const u32x4*)((char*)bounce + (eg * 16 + l15) * 256 + (s1 << 4));
      union { u16 u[8]; bf16x8 v; } ph, pl;
#pragma unroll
      for (int j = 0; j < 4; j++) {
        ph.u[j] = (u16)(a[j] & 0xffff);     pl.u[j] = (u16)(a[j] >> 16);
        ph.u[4 + j] = (u16)(b[j] & 0xffff); pl.u[4 + j] = (u16)(b[j] >> 16);
      }
      hh[eg][ks] = ph.v; hl[eg][ks] = pl.v;
    }
  }

  float outs[EG][4], outv[EG][4][3], tsv[EG][4];
#pragma unroll
  for (int eg = 0; eg < EG; eg++)
#pragma unroll
    for (int r = 0; r < 4; r++) {
      outs[eg][r] = 0.f; tsv[eg][r] = 0.f;
      outv[eg][r][0] = 0.f; outv[eg][r][1] = 0.f; outv[eg][r][2] = 0.f;
    }

#pragma unroll 1
  for (int tc = 0; tc < 8; tc++) {
    __syncthreads();
#pragma unroll
    for (int it = 0; it < 8; it++) {
      int s = it * 256 + tid;
      int rc = s >> 3, sl = s & 7;
      const u16* src = (rc < 128) ? (w2h + (long)(tc * 128 + rc) * 64)
                                  : (w2l + (long)(tc * 128 + rc - 128) * 64);
      u32x4 v = *(const u32x4*)(src + sl * 8);
      *(u32x4*)((char*)w2ld + rc * 128 + ((sl ^ (rc & 7)) << 4)) = v;
    }
    __syncthreads();

    const int t = tc >> 1;
    const int ibase = (tc & 1) * 8;
#pragma unroll 1
    for (int ih = 0; ih < 2; ih++) {
      float ax[EG][4], axv[EG][12];
      if (t == 0 || t == 2) {
        int coff = ibase + ih * 4;
#pragma unroll
        for (int eg = 0; eg < EG; eg++) {
          f32x4 q = *(const f32x4*)(na + (long)dstn[eg] * 64 + coff);
          ax[eg][0] = q[0]; ax[eg][1] = q[1]; ax[eg][2] = q[2]; ax[eg][3] = q[3];
        }
      } else {
        int base3 = (ibase + ih * 4) * 3;
#pragma unroll
        for (int eg = 0; eg < EG; eg++) {
          const float* nb = na + (long)dstn[eg] * 64 + 16 + base3;
          f32x4 q0 = *(const f32x4*)(nb);
          f32x4 q1 = *(const f32x4*)(nb + 4);
          f32x4 q2 = *(const f32x4*)(nb + 8);
#pragma unroll
          for (int q = 0; q < 4; q++) {
            axv[eg][q] = q0[q]; axv[eg][4 + q] = q1[q]; axv[eg][8 + q] = q2[q];
          }
        }
      }
#pragma unroll
      for (int iw = 0; iw < 4; iw++) {
        const int il = ih * 4 + iw;
        const char* bh = (char*)w2ld + (il * 16 + l15) * 128;
        const char* bl = bh + 128 * 128;
        bf16x8 wh0 = *(const bf16x8*)(bh + ((rg ^ x7) << 4));
        bf16x8 wh1 = *(const bf16x8*)(bh + (((4 + rg) ^ x7) << 4));
        bf16x8 wl0 = *(const bf16x8*)(bl + ((rg ^ x7) << 4));
        bf16x8 wl1 = *(const bf16x8*)(bl + (((4 + rg) ^ x7) << 4));
        f32x4 dinit = *(const f32x4*)(b2 + (tc * 8 + il) * 16 + rg * 4);
        f32x4 d[EG];
#pragma unroll
        for (int eg = 0; eg < EG; eg++) {
          f32x4 acc = dinit;
          acc = __builtin_amdgcn_mfma_f32_16x16x32_bf16(wh0, hh[eg][0], acc, 0, 0, 0);
          acc = __builtin_amdgcn_mfma_f32_16x16x32_bf16(wh1, hh[eg][1], acc, 0, 0, 0);
          acc = __builtin_amdgcn_mfma_f32_16x16x32_bf16(wl0, hh[eg][0], acc, 0, 0, 0);
          acc = __builtin_amdgcn_mfma_f32_16x16x32_bf16(wl1, hh[eg][1], acc, 0, 0, 0);
          acc = __builtin_amdgcn_mfma_f32_16x16x32_bf16(wh0, hl[eg][0], acc, 0, 0, 0);
          acc = __builtin_amdgcn_mfma_f32_16x16x32_bf16(wh1, hl[eg][1], acc, 0, 0, 0);
          d[eg] = acc;
        }
        if (t == 0) {
#pragma unroll
          for (int eg = 0; eg < EG; eg++) {
            float a = ax[eg][iw] * ss[eg];
#pragma unroll
            for (int r = 0; r < 4; r++) outs[eg][r] += a * d[eg][r];
          }
        } else if (t == 1) {
#pragma unroll
          for (int eg = 0; eg < EG; eg++) {
            float a = SQ3 * (axv[eg][3 * iw] * sv0[eg] + axv[eg][3 * iw + 1] * sv1[eg] +
                             axv[eg][3 * iw + 2] * sv2[eg]);
#pragma unroll
            for (int r = 0; r < 4; r++) outs[eg][r] += a * d[eg][r];
          }
        } else if (t == 2) {
#pragma unroll
          for (int eg = 0; eg < EG; eg++) {
            float a = ax[eg][iw];
#pragma unroll
            for (int r = 0; r < 4; r++) tsv[eg][r] += a * d[eg][r];
          }
        } else {
#pragma unroll
          for (int eg = 0; eg < EG; eg++) {
            float a0 = SQ3 * ss[eg] * axv[eg][3 * iw];
            float a1 = SQ3 * ss[eg] * axv[eg][3 * iw + 1];
            float a2 = SQ3 * ss[eg] * axv[eg][3 * iw + 2];
#pragma unroll
            for (int r = 0; r < 4; r++) {
              outv[eg][r][0] += a0 * d[eg][r];
              outv[eg][r][1] += a1 * d[eg][r];
              outv[eg][r][2] += a2 * d[eg][r];
            }
          }
        }
      }
    }
  }

#pragma unroll
  for (int eg = 0; eg < EG; eg++)
#pragma unroll
    for (int r = 0; r < 4; r++) {
      outv[eg][r][0] += SQ3 * tsv[eg][r] * sv0[eg];
      outv[eg][r][1] += SQ3 * tsv[eg][r] * sv1[eg];
      outv[eg][r][2] += SQ3 * tsv[eg][r] * sv2[eg];
    }

#pragma unroll
  for (int eg = 0; eg < EG; eg++) {
    if (!vld[eg]) continue;
    char* row = (char*)(tp + (long)posv[eg] * 64);
    int kb = rg * 4;
    u32x2 w0;
    w0[0] = pack2(ALPHAC * outs[eg][0], ALPHAC * outs[eg][1]);
    w0[1] = pack2(ALPHAC * outs[eg][2], ALPHAC * outs[eg][3]);
    *(u32x2*)(row + kb * 2) = w0;
    u32x2 w1v, w2v, w3v;
    w1v[0] = pack2(ALPHAC * outv[eg][0][0], ALPHAC * outv[eg][0][1]);
    w1v[1] = pack2(ALPHAC * outv[eg][0][2], ALPHAC * outv[eg][1][0]);
    w2v[0] = pack2(ALPHAC * outv[eg][1][1], ALPHAC * outv[eg][1][2]);
    w2v[1] = pack2(ALPHAC * outv[eg][2][0], ALPHAC * outv[eg][2][1]);
    w3v[0] = pack2(ALPHAC * outv[eg][2][2], ALPHAC * outv[eg][3][0]);
    w3v[1] = pack2(ALPHAC * outv[eg][3][1], ALPHAC * outv[eg][3][2]);
    *(u32x2*)(row + (16 + 3 * kb) * 2) = w1v;
    *(u32x2*)(row + (16 + 3 * kb) * 2 + 8) = w2v;
    *(u32x2*)(row + (16 + 3 * kb) * 2 + 16) = w3v;
  }
}

// ---------------------------------------------------------------------------
// K3: order-independent segment sum (int64 fixed-point, exact) -> mean ->
// +node_attr -> d_out; BN stat partials via fixed-order LDS tree + int64
// global atomics (associative => deterministic).
// ---------------------------------------------------------------------------
__global__ __launch_bounds__(256) void k_agg(
    const u16* __restrict__ tp, const int* __restrict__ off, const int* __restrict__ bpre,
    const float* __restrict__ na, float* __restrict__ outp, u64* __restrict__ stats) {
  const int tid = threadIdx.x;
  const int lq = tid & 15, grp = tid >> 4;
  const int c0 = lq * 4;
  float sum4[4] = {0.f, 0.f, 0.f, 0.f}, sq4[4] = {0.f, 0.f, 0.f, 0.f};
  for (int chunk = blockIdx.x; chunk < N_NODES / 16; chunk += gridDim.x) {
    int n = chunk * 16 + grp;
    int o0 = off[n] + bpre[n >> 8];
    int o1 = off[n + 1] + bpre[(n + 1) >> 8];
    long long acc[4] = {0, 0, 0, 0};
    for (int r = o0; r < o1; r++) {
      u32x2 v = *(const u32x2*)(tp + (long)r * 64 + c0);
      acc[0] += (long long)rintf(bf2f((u16)(v[0] & 0xffff)) * FXS);
      acc[1] += (long long)rintf(bf2f((u16)(v[0] >> 16)) * FXS);
      acc[2] += (long long)rintf(bf2f((u16)(v[1] & 0xffff)) * FXS);
      acc[3] += (long long)rintf(bf2f((u16)(v[1] >> 16)) * FXS);
    }
    float inv = 1.0f / fmaxf((float)(o1 - o0), 1.0f);
    f32x4 x = *(const f32x4*)(na + (long)n * 64 + c0);
    f32x4 p;
#pragma unroll
    for (int j = 0; j < 4; j++) {
      float a = (float)acc[j] * FXI;
      p[j] = a * inv + x[j];
      sum4[j] += p[j];
      sq4[j] += p[j] * p[j];
    }
    *(f32x4*)(outp + (long)n * 64 + c0) = p;
  }
  __shared__ float psum[16][64], psq[16][64];
  *(f32x4*)&psum[grp][c0] = (f32x4){sum4[0], sum4[1], sum4[2], sum4[3]};
  *(f32x4*)&psq[grp][c0]  = (f32x4){sq4[0], sq4[1], sq4[2], sq4[3]};
  __syncthreads();
  if (tid < 64) {
    float ts = 0.f, tq = 0.f;
    for (int g = 0; g < 16; g++) { ts += psum[g][tid]; tq += psq[g][tid]; }
    atomicAdd(&stats[tid], (u64)(long long)rintf(ts * FXS));
    atomicAdd(&stats[64 + tid], (u64)(long long)rintf(tq * FXS));
  }
}

// ---------------------------------------------------------------------------
// K4: finalize batch-norm (stats from int64 fixed-point), in place on d_out
// ---------------------------------------------------------------------------
__global__ __launch_bounds__(256) void k_norm2(
    const float* __restrict__ inp, const u64* __restrict__ stats,
    const float* __restrict__ bnw, const float* __restrict__ bnb,
    float* __restrict__ out) {
  const int tid = threadIdx.x;
  const int lq = tid & 15, nsub = tid >> 4;
  const int c0 = lq * 4;
  float sc[4], bi[4];
#pragma unroll
  for (int j = 0; j < 4; j++) {
    int c = c0 + j;
    float sumc = (float)((double)(long long)stats[c] * (1.0 / 1048576.0));
    float sqc  = (float)((double)(long long)stats[64 + c] * (1.0 / 1048576.0));
    if (c < 16) {
      float mean = sumc * (1.0f / N_NODES);
      float var = sqc * (1.0f / N_NODES) - mean * mean;
      float rstd = rsqrtf(var + EPSC);
      sc[j] = rstd * bnw[c];
      bi[j] = bnb[c] - mean * rstd * bnw[c];
    } else {
      int k = (c - 16) / 3;
      float q0 = (float)((double)(long long)stats[64 + 16 + 3 * k] * (1.0 / 1048576.0));
      float q1 = (float)((double)(long long)stats[64 + 17 + 3 * k] * (1.0 / 1048576.0));
      float q2 = (float)((double)(long long)stats[64 + 18 + 3 * k] * (1.0 / 1048576.0));
      float fn = (q0 + q1 + q2) * (1.0f / (3.0f * N_NODES));
      sc[j] = rsqrtf(fn + EPSC) * bnw[16 + k];
      bi[j] = 0.f;
    }
  }
  for (int chunk = blockIdx.x; chunk < N_NODES / 16; chunk += gridDim.x) {
    long n = (long)chunk * 16 + nsub;
    f32x4 p = *(const f32x4*)(inp + n * 64 + c0);
    f32x4 o;
#pragma unroll
    for (int j = 0; j < 4; j++) o[j] = p[j] * sc[j] + bi[j];
    *(f32x4*)(out + n * 64 + c0) = o;
  }
}

// ---------------------------------------------------------------------------
extern "C" void kernel_launch(void* const* d_in, const int* in_sizes, int n_in,
                              void* d_out, int out_size, void* d_ws, size_t ws_size,
                              hipStream_t stream) {
  const float* na  = (const float*)d_in[0];
  const float* ea  = (const float*)d_in[1];
  const float* sh  = (const float*)d_in[2];
  const float* w1  = (const float*)d_in[3];
  const float* b1  = (const float*)d_in[4];
  const float* w2  = (const float*)d_in[5];
  const float* b2  = (const float*)d_in[6];
  const float* bnw = (const float*)d_in[7];
  const float* bnb = (const float*)d_in[8];
  const int*   ei  = (const int*)d_in[9];

  char* ws = (char*)d_ws;
  u16*   tp     = (u16*)ws;                     // 25,600,000
  int*   pos    = (int*)(ws + 25600000);        //    800,000
  int*   off    = (int*)(ws + 26400000);        //    200,064 (N+1 ints)
  int*   cursor = (int*)(ws + 26600064);        //    200,064
  int*   deg    = (int*)(ws + 26800128);        //    200,000
  u64*   stats  = (u64*)(ws + 27000128);        //      1,024 (ll[128])
  u16*   w1h    = (u16*)(ws + 27001152);        //      8,192
  u16*   w1l    = (u16*)(ws + 27009344);        //      8,192
  u16*   w2h    = (u16*)(ws + 27017536);        //    131,072
  u16*   w2l    = (u16*)(ws + 27148608);        //    131,072
  int*   bsum   = (int*)(ws + 27279680);        //      1,024
  int*   bpre   = (int*)(ws + 27280704);        //      1,024
  if (ws_size < 27281728) return;  // fail visibly (output stays poisoned)

  hipMemsetAsync(ws + 26800128, 0, 201024, stream);  // deg + stats
  hipLaunchKernelGGL(k_prep,  dim3(782), dim3(256), 0, stream, w1, w2, ei, w1h, w1l, w2h, w2l, deg);
  hipLaunchKernelGGL(k_scan1, dim3(196), dim3(256), 0, stream, deg, off, cursor, bsum);
  hipLaunchKernelGGL(k_scan2, dim3(1),   dim3(256), 0, stream, bsum, bpre);
  hipLaunchKernelGGL(k_fill,  dim3(782), dim3(256), 0, stream, ei, cursor, bpre, pos);
  hipLaunchKernelGGL(k_fused, dim3(1563), dim3(256), 0, stream,
                     ea, b1, b2, na, sh, ei, pos, w1h, w1l, w2h, w2l, tp);
  hipLaunchKernelGGL(k_agg,   dim3(512), dim3(256), 0, stream, tp, off, bpre, na, (float*)d_out, stats);
  hipLaunchKernelGGL(k_norm2, dim3(512), dim3(256), 0, stream, (float*)d_out, stats, bnw, bnb, (float*)d_out);
}